// Round 6
// baseline (221.859 us; speedup 1.0000x reference)
//
#include <hip/hip_runtime.h>
#include <cfloat>
#include <math.h>

#define BINS 64
#define NELEM (192*224*192)       // 8,257,536 per batch sample (C=1)
#define N4    (NELEM/4)           // 2,064,384 float4 per slice
#define NB 2
#define HIST_OFF 16               // ws u32 index where histograms start
#define BLK 256

typedef float f32x4 __attribute__((ext_vector_type(4)));

__device__ __forceinline__ f32x4 ntload(const f32x4* p){
    return __builtin_nontemporal_load(p);
}

// ws layout (u32): [0..7]  minmax keys: b*4 + {fmin,fmax,wmin,wmax}
//                  [8..11] float accums: {hj_b0, hj_b1}
//                  [16..16+NB*4096) joint histograms

__device__ __forceinline__ unsigned fkey(float f){
    unsigned u = __float_as_uint(f);
    return (u & 0x80000000u) ? ~u : (u | 0x80000000u);
}
__device__ __forceinline__ float funkey(unsigned k){
    unsigned u = (k & 0x80000000u) ? (k ^ 0x80000000u) : ~k;
    return __uint_as_float(u);
}

__global__ void k_init(unsigned* ws){
    int i = blockIdx.x * 256 + threadIdx.x;
    if (i < 16) ws[i] = (i < 8) ? (((i & 1) == 0) ? 0xFFFFFFFFu : 0u) : 0u;
    if (i < NB * BINS * BINS) ws[HIST_OFF + i] = 0u;
}

__device__ __forceinline__ void mm4(const f32x4& v, float& mn, float& mx){
    mn = fminf(mn, fminf(fminf(v[0], v[1]), fminf(v[2], v[3])));
    mx = fmaxf(mx, fmaxf(fmaxf(v[0], v[1]), fmaxf(v[2], v[3])));
}

// grid (512, 4): y -> (arr = y>>1, b = y&1). ONE contiguous stream per block.
// Non-temporal loads: read-once data, don't allocate in L2/L3.
__global__ __launch_bounds__(BLK) void k_minmax(const float* __restrict__ F,
                                                const float* __restrict__ W,
                                                unsigned* ws){
    const int arr = blockIdx.y >> 1;
    const int b   = blockIdx.y & 1;
    const f32x4* S4 = (const f32x4*)((arr ? W : F) + (size_t)b * NELEM);
    const int STRIDE = 512 * BLK;             // 131072 float4 = 2 MB
    float mn = FLT_MAX, mx = -FLT_MAX;

    int i = blockIdx.x * BLK + threadIdx.x;
    for (; i + STRIDE < N4; i += 2 * STRIDE){
        f32x4 v0 = ntload(S4 + i);
        f32x4 v1 = ntload(S4 + i + STRIDE);
        mm4(v0, mn, mx); mm4(v1, mn, mx);
    }
    if (i < N4){ f32x4 v0 = ntload(S4 + i); mm4(v0, mn, mx); }

    for (int off = 32; off; off >>= 1){
        mn = fminf(mn, __shfl_down(mn, off));
        mx = fmaxf(mx, __shfl_down(mx, off));
    }
    __shared__ float s[4][2];
    int wave = threadIdx.x >> 6;
    if ((threadIdx.x & 63) == 0){ s[wave][0] = mn; s[wave][1] = mx; }
    __syncthreads();
    if (threadIdx.x == 0){
        float a0 = s[0][0], a1 = s[0][1];
        for (int wv = 1; wv < 4; ++wv){
            a0 = fminf(a0, s[wv][0]); a1 = fmaxf(a1, s[wv][1]);
        }
        const int slot = b * 4 + arr * 2;
        atomicMin(&ws[slot],     fkey(a0));
        atomicMax(&ws[slot + 1], fkey(a1));
    }
}

__device__ __forceinline__ void bin4(const f32x4& fa, const f32x4& wa,
                                     float fmn, float wmn, float fden, float wden,
                                     unsigned* h){
    #pragma unroll
    for (int j = 0; j < 4; ++j){
        int fi = (int)((fa[j] - fmn) / fden * 63.0f);
        int wi = (int)((wa[j] - wmn) / wden * 63.0f);
        fi = min(max(fi, 0), 63);
        wi = min(max(wi, 0), 63);
        atomicAdd(&h[fi * BINS + wi], 1u);
    }
}

// grid (256, NB): y = batch. Grid-stride, unroll-2, NT loads.
__global__ __launch_bounds__(BLK) void k_hist(const float* __restrict__ F,
                                              const float* __restrict__ W,
                                              unsigned* ws){
    const int b = blockIdx.y;
    __shared__ unsigned h[BINS * BINS];
    for (int i = threadIdx.x; i < BINS * BINS; i += BLK) h[i] = 0u;

    const float fmn = funkey(ws[b*4+0]);
    const float fmx = funkey(ws[b*4+1]);
    const float wmn = funkey(ws[b*4+2]);
    const float wmx = funkey(ws[b*4+3]);
    const float fden = fmx - fmn + 1e-10f;   // exact ref f32 arithmetic
    const float wden = wmx - wmn + 1e-10f;

    const f32x4* F4 = (const f32x4*)(F + (size_t)b * NELEM);
    const f32x4* W4 = (const f32x4*)(W + (size_t)b * NELEM);
    const int STRIDE = 256 * BLK;            // 65536 float4
    __syncthreads();

    int i = blockIdx.x * BLK + threadIdx.x;
    for (; i + STRIDE < N4; i += 2 * STRIDE){
        f32x4 a0 = ntload(F4 + i);
        f32x4 c0 = ntload(W4 + i);
        f32x4 a1 = ntload(F4 + i + STRIDE);
        f32x4 c1 = ntload(W4 + i + STRIDE);
        bin4(a0, c0, fmn, wmn, fden, wden, h);
        bin4(a1, c1, fmn, wmn, fden, wden, h);
    }
    if (i < N4){
        f32x4 a0 = ntload(F4 + i);
        f32x4 c0 = ntload(W4 + i);
        bin4(a0, c0, fmn, wmn, fden, wden, h);
    }

    __syncthreads();
    unsigned* gh = ws + HIST_OFF + b * BINS * BINS;
    for (int i2 = threadIdx.x; i2 < BINS * BINS; i2 += BLK){
        unsigned v = h[i2];
        if (v) atomicAdd(&gh[i2], v);
    }
}

// grid 32 x 256: joint-entropy partial sums -> atomicAdd into ws[8+b] (float)
__global__ __launch_bounds__(BLK) void k_finalA(unsigned* ws){
    const int id = blockIdx.x * BLK + threadIdx.x;   // [0, 8192)
    const int b  = id >> 12;
    const float fN = (float)NELEM;
    float p = (float)ws[HIST_OFF + id] / fN;
    float v = p * __logf(p + 1e-10f);
    for (int off = 32; off; off >>= 1) v += __shfl_down(v, off);
    if ((threadIdx.x & 63) == 0)
        atomicAdd((float*)(ws + 8 + b), v);          // 128 atomics total
}

// 1 block x 256: marginals + combine + affine MSE
__global__ __launch_bounds__(BLK) void k_finalB(const float* __restrict__ pa,
                                                const float* __restrict__ ta,
                                                unsigned* ws, float* __restrict__ out){
    const int t = threadIdx.x;
    const unsigned* hist = ws + HIST_OFF;
    const float fN = (float)NELEM;
    // wave 0: rows b0 | wave 1: rows b1 | wave 2: cols b0 | wave 3: cols b1
    const int wave = t >> 6, lane = t & 63;
    const int b = wave & 1;
    unsigned c = 0;
    if (wave < 2){ const unsigned* H = hist + b * 4096 + lane * 64;
        for (int j = 0; j < 64; ++j) c += H[j]; }
    else { const unsigned* H = hist + b * 4096 + lane;
        for (int j = 0; j < 64; ++j) c += H[j * 64]; }
    float p = (float)c / fN;
    float v = p * __logf(p + 1e-10f);
    for (int off = 32; off; off >>= 1) v += __shfl_down(v, off);
    __shared__ float sw[4];
    if (lane == 0) sw[wave] = v;
    __syncthreads();
    if (t == 0){
        double loss_sim = 0.0;
        for (int bb = 0; bb < NB; ++bb){
            double S  = -((double)sw[bb] + (double)sw[2 + bb]);  // h_f + h_w
            double hj = -(double)((float*)(ws + 8))[bb];
            double mi = S - hj;
            double nmi = 2.0 * mi / (S + 1e-10);
            loss_sim += -nmi;
        }
        loss_sim /= (double)NB;
        double a = 0.0;
        for (int i = 0; i < 24; ++i){
            double d = (double)pa[i] - (double)ta[i];
            a += d * d;
        }
        a /= 24.0;
        out[0] = (float)(a + loss_sim);
    }
}

extern "C" void kernel_launch(void* const* d_in, const int* in_sizes, int n_in,
                              void* d_out, int out_size, void* d_ws, size_t ws_size,
                              hipStream_t stream) {
    const float* pa = (const float*)d_in[0];
    const float* ta = (const float*)d_in[1];
    const float* F  = (const float*)d_in[2];
    const float* W  = (const float*)d_in[3];
    float* out = (float*)d_out;
    unsigned* ws = (unsigned*)d_ws;

    k_init<<<33, 256, 0, stream>>>(ws);
    k_minmax<<<dim3(512, 4), BLK, 0, stream>>>(F, W, ws);
    k_hist<<<dim3(256, NB), BLK, 0, stream>>>(F, W, ws);
    k_finalA<<<32, BLK, 0, stream>>>(ws);
    k_finalB<<<1, BLK, 0, stream>>>(pa, ta, ws, out);
}